// Round 17
// baseline (144.224 us; speedup 1.0000x reference)
//
#include <hip/hip_runtime.h>
#include <hip/hip_bf16.h>

typedef unsigned short ushort_t;
typedef unsigned int uint32;
typedef __attribute__((ext_vector_type(8))) short short8;
typedef __attribute__((ext_vector_type(4))) float f32x4;
typedef __attribute__((ext_vector_type(16))) float f32x16;

#define BATCH 8
#define SEQ 1024
#define DIM 512
#define NHEADS 8
#define DH 64
#define NQKV 1536

__device__ __forceinline__ float bf2f(ushort_t u){ return __uint_as_float(((uint32)u) << 16); }
__device__ __forceinline__ ushort_t f2bf(float f){
  uint32 u = __float_as_uint(f);
  return (ushort_t)((u + 0x7fffu + ((u >> 16) & 1u)) >> 16);
}
__device__ __forceinline__ short8 ld8(const ushort_t* p){ return *reinterpret_cast<const short8*>(p); }
__device__ __forceinline__ f32x4 mfma16(short8 a, short8 b, f32x4 c){
  return __builtin_amdgcn_mfma_f32_16x16x32_bf16(a, b, c, 0, 0, 0);
}
__device__ __forceinline__ f32x16 mfma32(short8 a, short8 b, f32x16 c){
  return __builtin_amdgcn_mfma_f32_32x32x16_bf16(a, b, c, 0, 0, 0);
}
// async global->LDS, 16 B per lane; LDS dst is wave-uniform base + lane*16.
__device__ __forceinline__ void async16(const ushort_t* g, ushort_t* l){
  __builtin_amdgcn_global_load_lds((const __attribute__((address_space(1))) void*)g,
                                   (__attribute__((address_space(3))) void*)l, 16, 0, 0);
}
__device__ __forceinline__ uint32 cvtpk_bf16(float lo, float hi){
  uint32 d;
  asm("v_cvt_pk_bf16_f32 %0, %1, %2" : "=v"(d) : "v"(lo), "v"(hi));
  return d;
}
// v_permlane32_swap_b32: a[hi lanes] <-> b[lo lanes]
__device__ __forceinline__ void permswap32(uint32& a, uint32& b){
  asm volatile("v_permlane32_swap_b32 %0, %1" : "+v"(a), "+v"(b));
}
__device__ __forceinline__ short8 mk8(uint32 a, uint32 b, uint32 c, uint32 d){
  union { uint32 u[4]; short8 v; } t;
  t.u[0] = a; t.u[1] = b; t.u[2] = c; t.u[3] = d; return t.v;
}

// ---------------- prep: LN (blocks 0..2047) + wqkv transpose (2048..2815) + wout transpose ----------------
__global__ __launch_bounds__(256) void prep_kernel(const float* __restrict__ x,
                                                   const float* __restrict__ g,
                                                   const float* __restrict__ bt,
                                                   ushort_t* __restrict__ xn,
                                                   const float* __restrict__ wqkv,
                                                   ushort_t* __restrict__ wqkvT,
                                                   const float* __restrict__ wout,
                                                   ushort_t* __restrict__ woutT){
  __shared__ float t[32][33];
  int bid = blockIdx.x;
  if (bid < 2048){
    int row  = bid * 4 + (threadIdx.x >> 6);
    int lane = threadIdx.x & 63;
    const float* xr = x + (size_t)row * DIM + lane * 8;
    float4 d0 = *reinterpret_cast<const float4*>(xr);
    float4 d1 = *reinterpret_cast<const float4*>(xr + 4);
    float v[8] = {d0.x, d0.y, d0.z, d0.w, d1.x, d1.y, d1.z, d1.w};
    float s = 0.f, ss = 0.f;
    #pragma unroll
    for (int i = 0; i < 8; i++){ s += v[i]; ss += v[i] * v[i]; }
    #pragma unroll
    for (int off = 1; off < 64; off <<= 1){ s += __shfl_xor(s, off); ss += __shfl_xor(ss, off); }
    float mean = s * (1.0f / DIM);
    float var  = ss * (1.0f / DIM) - mean * mean;
    float rstd = rsqrtf(fmaxf(var, 0.f) + 1e-5f);
    float4 g0 = *reinterpret_cast<const float4*>(g  + lane * 8);
    float4 g1 = *reinterpret_cast<const float4*>(g  + lane * 8 + 4);
    float4 b0 = *reinterpret_cast<const float4*>(bt + lane * 8);
    float4 b1 = *reinterpret_cast<const float4*>(bt + lane * 8 + 4);
    float gv[8] = {g0.x, g0.y, g0.z, g0.w, g1.x, g1.y, g1.z, g1.w};
    float bv[8] = {b0.x, b0.y, b0.z, b0.w, b1.x, b1.y, b1.z, b1.w};
    ushort_t o[8];
    #pragma unroll
    for (int i = 0; i < 8; i++) o[i] = f2bf((v[i] - mean) * rstd * gv[i] + bv[i]);
    uint4 od;
    od.x = o[0] | ((uint32)o[1] << 16); od.y = o[2] | ((uint32)o[3] << 16);
    od.z = o[4] | ((uint32)o[5] << 16); od.w = o[6] | ((uint32)o[7] << 16);
    *reinterpret_cast<uint4*>(xn + (size_t)row * DIM + lane * 8) = od;
  } else {
    const float* in; ushort_t* out; int R, C, bx, by;
    if (bid < 2816){ int b = bid - 2048; in = wqkv; out = wqkvT; R = 512; C = 1536; bx = b % 48; by = b / 48; }
    else           { int b = bid - 2816; in = wout; out = woutT; R = 512; C = 512;  bx = b % 16; by = b / 16; }
    int tx = threadIdx.x & 31, ty = threadIdx.x >> 5;
    int r0 = by * 32, c0 = bx * 32;
    #pragma unroll
    for (int i = 0; i < 4; i++) t[ty + 8*i][tx] = in[(size_t)(r0 + ty + 8*i) * C + c0 + tx];
    __syncthreads();
    #pragma unroll
    for (int i = 0; i < 4; i++) out[(size_t)(c0 + ty + 8*i) * R + r0 + tx] = f2bf(t[tx][ty + 8*i]);
  }
}

// ======================================================================
// Tiled GEMM core (m97 structure): C = A[M,512] @ Bt[N,512]^T.
// ======================================================================
template<int MT>
__device__ __forceinline__ void gemm_core_t(const ushort_t* __restrict__ A,
                                            const ushort_t* __restrict__ Bt,
                                            int m0, int n0,
                                            ushort_t* ldsA, ushort_t* ldsB,
                                            f32x4 acc[MT][4]){
  int tid = threadIdx.x, w = tid >> 6, lane = tid & 63;
  int c16 = lane & 15, quad = lane >> 4;
  int r8 = lane >> 3, p8 = lane & 7;
  int srcChunk = p8 ^ r8;                 // LDS[row][p] = G[row][p ^ (row&7)]
  int w_row = w >> 1, w_col = w & 1;

  const ushort_t* ga[MT]; const ushort_t* gb[4];
  #pragma unroll
  for (int c = 0; c < MT; c++)
    ga[c] = A  + (size_t)(m0 + c * 32 + w * 8 + r8) * DIM + srcChunk * 8;
  #pragma unroll
  for (int c = 0; c < 4; c++)
    gb[c] = Bt + (size_t)(n0 + c * 32 + w * 8 + r8) * DIM + srcChunk * 8;
  #pragma unroll
  for (int mt = 0; mt < MT; mt++)
    #pragma unroll
    for (int nt = 0; nt < 4; nt++) acc[mt][nt] = (f32x4){0.f, 0.f, 0.f, 0.f};

  for (int it = 0; it < 8; it++){         // K = 8 * 64
    #pragma unroll
    for (int c = 0; c < MT; c++){ async16(ga[c], &ldsA[(c * 32 + w * 8) * 64]); ga[c] += 64; }
    #pragma unroll
    for (int c = 0; c < 4;  c++){ async16(gb[c], &ldsB[(c * 32 + w * 8) * 64]); gb[c] += 64; }
    __syncthreads();
    #pragma unroll
    for (int kk = 0; kk < 2; kk++){
      short8 af[MT], bfr[4];
      int phys = ((kk * 4 + quad) ^ (c16 & 7)) * 8;
      #pragma unroll
      for (int mt = 0; mt < MT; mt++)
        af[mt] = ld8(&ldsA[(w_row * (MT * 16) + mt * 16 + c16) * 64 + phys]);
      #pragma unroll
      for (int nt = 0; nt < 4; nt++)
        bfr[nt] = ld8(&ldsB[(w_col * 64 + nt * 16 + c16) * 64 + phys]);
      #pragma unroll
      for (int mt = 0; mt < MT; mt++)
        #pragma unroll
        for (int nt = 0; nt < 4; nt++)
          acc[mt][nt] = mfma16(af[mt], bfr[nt], acc[mt][nt]);
    }
    __syncthreads();
  }
}

// ---------------- QKV GEMM: xn[8192,512] @ w[512,1536] + b, scatter to Q,Kb,Vt ----------------
// MT=2 (64x128 tiles): best measured for this short-K GEMM (round-9 A/B).
// v34: XCD-CHUNKED BLOCK SWIZZLE (T1). A (16 MB) is re-read 12x (once per
// n-block); default x-fastest dispatch puts the 12 blocks sharing an
// A-panel 128 dispatch slots apart -> different XCDs, panel never L2-hot.
// Bijective remap (1536 % 8 == 0): xcd=flat%8, slot=flat/8; n_blk=slot%12,
// mloc=slot/12; m_blk=xcd*16+mloc. XCD k owns m-panels [16k,16k+16) x all
// 12 n-blocks: A-panel re-reads become back-to-back L2 hits, B working set
// (1.5 MB) L2-resident. Index remap only -- no math change.
// Q pre-scaled by 0.125*log2(e). K stored FRAGMENT-BLOCKED: elem K[n][dd] at
// (n>>5)*2048 + (dd>>4)*512 + ((dd>>3)&1)*256 + (n&31)*8 + (dd&7).
__global__ __launch_bounds__(256) void qkv_gemm_kernel(const ushort_t* __restrict__ xn,
                                                       const ushort_t* __restrict__ wT,
                                                       const float* __restrict__ bias,
                                                       ushort_t* __restrict__ Qo,
                                                       ushort_t* __restrict__ Ko,
                                                       ushort_t* __restrict__ Vt){
  __shared__ __align__(16) ushort_t ldsA[64 * 64];
  __shared__ __align__(16) ushort_t ldsB[128 * 64];
  int flat = blockIdx.y * 128 + blockIdx.x;     // dispatch order (x fastest)
  int xcd  = flat & 7, slot = flat >> 3;        // round-robin XCD assignment
  int n_blk = slot % 12, mloc = slot / 12;      // slot in [0,192): n fastest
  int m0 = (xcd * 16 + mloc) * 64;
  int n0 = n_blk * 128;
  f32x4 acc[2][4];
  gemm_core_t<2>(xn, wT, m0, n0, ldsA, ldsB, acc);

  int lane = threadIdx.x & 63, w = threadIdx.x >> 6;
  int c16 = lane & 15, quad = lane >> 4;
  int w_row = w >> 1, w_col = w & 1;
  int region = n0 >> 9;                   // 0=Q 1=K 2=V (BN=128 divides 512)

  if (region < 2){
    float sc = (region == 0) ? 0.18033688011112042f : 1.0f;   // 0.125*log2(e) folded into Q
    #pragma unroll
    for (int nt = 0; nt < 4; nt++){
      int col = n0 + w_col * 64 + nt * 16 + c16;
      float bv = bias[col];
      int cr = col & 511, h = cr >> 6, dd = cr & 63;
      #pragma unroll
      for (int mt = 0; mt < 2; mt++){
        #pragma unroll
        for (int r = 0; r < 4; r++){
          int row = m0 + w_row * 32 + mt * 16 + quad * 4 + r;
          int b = row >> 10, n = row & 1023;
          ushort_t o = f2bf((acc[mt][nt][r] + bv) * sc);
          if (region == 0){
            Qo[(((size_t)(b * NHEADS + h)) * SEQ + n) * DH + dd] = o;
          } else {
            Ko[((size_t)(b * NHEADS + h)) * SEQ * DH
               + (n >> 5) * 2048 + (dd >> 4) * 512 + ((dd >> 3) & 1) * 256
               + (n & 31) * 8 + (dd & 7)] = o;
          }
        }
      }
    }
  } else {
    #pragma unroll
    for (int nt = 0; nt < 4; nt++){
      int col = n0 + w_col * 64 + nt * 16 + c16;
      float bv = bias[col];
      int c2 = col - 1024; int h = c2 >> 6, dd = c2 & 63;
      #pragma unroll
      for (int mt = 0; mt < 2; mt++){
        int row0 = m0 + w_row * 32 + mt * 16 + quad * 4;
        int b = row0 >> 10, n = row0 & 1023;
        ushort_t o[4];
        #pragma unroll
        for (int r = 0; r < 4; r++) o[r] = f2bf(acc[mt][nt][r] + bv);
        uint2 val;
        val.x = o[0] | ((uint32)o[1] << 16);
        val.y = o[2] | ((uint32)o[3] << 16);
        *reinterpret_cast<uint2*>(Vt + (((size_t)(b * NHEADS + h)) * 128 + (n >> 3)) * 512
                                  + dd * 8 + (n & 7)) = val;
      }
    }
  }
}

// ---------------- out projection: ctx[8192,512] @ w_out[512,512] + b -> fp32 out ----------------
// MT=1 (32x128 tiles, grid (256,4)): round-4/7 config, best measured.
// (B here is only 512 KB -- L2-resident on every XCD after first touch;
// no swizzle needed.)
__global__ __launch_bounds__(256) void out_gemm_kernel(const ushort_t* __restrict__ ctx,
                                                       const ushort_t* __restrict__ wT,
                                                       const float* __restrict__ bias,
                                                       float* __restrict__ out){
  __shared__ __align__(16) ushort_t ldsA[32 * 64];
  __shared__ __align__(16) ushort_t ldsB[128 * 64];
  int m0 = blockIdx.x * 32, n0 = blockIdx.y * 128;
  f32x4 acc[1][4];
  gemm_core_t<1>(ctx, wT, m0, n0, ldsA, ldsB, acc);

  int lane = threadIdx.x & 63, w = threadIdx.x >> 6;
  int c16 = lane & 15, quad = lane >> 4;
  int w_row = w >> 1, w_col = w & 1;
  #pragma unroll
  for (int nt = 0; nt < 4; nt++){
    int col = n0 + w_col * 64 + nt * 16 + c16;
    float bv = bias[col];
    #pragma unroll
    for (int r = 0; r < 4; r++){
      int row = m0 + w_row * 16 + quad * 4 + r;
      out[(size_t)row * DIM + col] = acc[0][nt][r] + bv;
    }
  }
}

// ======================================================================
// FINAL attn == v28 (round-10/14/16 best, locked): zero-LDS, zero-barrier,
// 1 wave per (b,h,qt), coalesced fragment-blocked K, exp-folded region
// weights (P = exp2(QK + log2(w)) via free MFMA C-init). Measured ~42us,
// 88 VGPR, no spill; total 143.0us (round 16).
// K-LDS staging is closed after 4 attempts (v29-v31, v33): any variant
// compiled WITH the 64KB static LDS gets VGPR pinned at 128 and emits a
// byte-identical ~120MB scratch signature regardless of the register
// program or launch attributes -- unsteerable from source. Splits and
// MT=4 GEMM tiles separately refuted with mechanisms.
// ======================================================================
__global__ __launch_bounds__(256, 2) void attn_kernel(const ushort_t* __restrict__ Qg,
                                                      const ushort_t* __restrict__ Kg,
                                                      const ushort_t* __restrict__ Vtg,
                                                      ushort_t* __restrict__ ctx){
  int bh = blockIdx.x;                 // inner => stable XCD = bh & 7 (2MB K+V per XCD L2)
  int wv = threadIdx.x >> 6, lane = threadIdx.x & 63;
  int qt = blockIdx.y * 4 + wv;        // query image row == hq, 0..31
  int w  = lane & 31;                  // query col (and output d col)
  int hi = lane >> 5;
  int hq = qt;

  const ushort_t* Qh = Qg  + (size_t)bh * SEQ * DH;
  const ushort_t* Kh = Kg  + (size_t)bh * SEQ * DH;  // fragment-blocked (see qkv)
  const ushort_t* Vh = Vtg + (size_t)bh * SEQ * DH;  // blocked [n/8][dd][8]

  // Q as B-operand: B[k][j]: j=lane&31=query, k=hi*8+jj, frag f = dims f*16..f*16+15
  short8 qf[4];
  {
    const ushort_t* qp = Qh + (size_t)(qt * 32 + w) * DH + hi * 8;
    #pragma unroll
    for (int f = 0; f < 4; f++) qf[f] = ld8(qp + f * 16);
  }
  const ushort_t* kp = Kh + (size_t)lane * 8;   // + tile*2048 + f*512 (coalesced)

  // per-lane j (key col) masks: this lane's 16 S^T rows are jr = (r&3)+8*(r>>2)+4*hi
  float mle[16], mge[16];
  #pragma unroll
  for (int r = 0; r < 16; r++){
    int jr = (r & 3) + 8 * (r >> 2) + 4 * hi;
    mle[r] = (jr <= w) ? 1.f : 0.f;
    mge[r] = (jr >= w) ? 1.f : 0.f;
  }

  auto qk = [&](const short8* kf) -> f32x16 {
    f32x16 s;
    #pragma unroll
    for (int r = 0; r < 16; r++) s[r] = 0.f;
    #pragma unroll
    for (int f = 0; f < 4; f++) s = mfma32(kf[f], qf[f], s);
    return s;
  };

  // ---- pass 1: region denominators ----
  float tle = 0.f, tge = 0.f, ble = 0.f, bge = 0.f;
  auto p1 = [&](const short8* kf, int i){
    f32x16 s = qk(kf);
    float a0 = 0.f, a1 = 0.f, g0 = 0.f, g1 = 0.f;
    #pragma unroll
    for (int r = 0; r < 16; r++){
      float e = __builtin_amdgcn_exp2f(s[r]);
      if (r & 1){ a1 = fmaf(mle[r], e, a1); g1 = fmaf(mge[r], e, g1); }
      else      { a0 = fmaf(mle[r], e, a0); g0 = fmaf(mge[r], e, g0); }
    }
    float sle = a0 + a1, sge = g0 + g1;
    if (i <= hq){ tle += sle; tge += sge; }   // uniform branches
    if (i >= hq){ ble += sle; bge += sge; }
  };
  {
    short8 kA[4], kB[4];
    #pragma unroll
    for (int f = 0; f < 4; f++) kA[f] = ld8(kp + f * 512);
    for (int i = 0; i < 32; i += 2){
      #pragma unroll
      for (int f = 0; f < 4; f++) kB[f] = ld8(kp + (size_t)(i + 1) * 2048 + f * 512);
      p1(kA, i);
      int nx = (i + 2) & 31;                 // wraps to 0 at the end (harmless, warms L1)
      #pragma unroll
      for (int f = 0; f < 4; f++) kA[f] = ld8(kp + (size_t)nx * 2048 + f * 512);
      p1(kB, i + 1);
    }
  }
  // combine the two lane-halves (same query, complementary key rows)
  tle += __shfl_xor(tle, 32); tge += __shfl_xor(tge, 32);
  ble += __shfl_xor(ble, 32); bge += __shfl_xor(bge, 32);
  float i1 = 0.25f / fmaxf(tle, 1e-30f);   // region (i<=h, j<=w), /4 folded in
  float i2 = 0.25f / fmaxf(tge, 1e-30f);   // (i<=h, j>=w)
  float i3 = 0.25f / fmaxf(ble, 1e-30f);   // (i>=h, j<=w)
  float i4 = 0.25f / fmaxf(bge, 1e-30f);   // (i>=h, j>=w)

  // log-weight state: lw = log2(weight for current tile group), wbt = bottom weights.
  // Tiles i<hq use wa; at i==hq weight = wa+wbt (exact); i>hq use wbt.
  float wbt[16];
  f32x16 lw;
  #pragma unroll
  for (int r = 0; r < 16; r++){
    float wa = fmaf(i1, mle[r], i2 * mge[r]);
    wbt[r]   = fmaf(i3, mle[r], i4 * mge[r]);
    lw[r]    = __builtin_amdgcn_logf(wa);      // v_log_f32 = log2
  }

  // ---- pass 2: recompute QK with C-init = lw, exp2 -> P, pack, PV ----
  f32x16 accLo, accHi;
  #pragma unroll
  for (int r = 0; r < 16; r++){ accLo[r] = 0.f; accHi[r] = 0.f; }
  const ushort_t* vbase = Vh + (size_t)hi * 512 + (size_t)w * 8;

  auto p2 = [&](const short8* kf, int i){
    // V B-frags for this tile (independent, issue early). keys i*32+c*16+hi*8..+7, d=w(+32)
    short8 vl0 = ld8(vbase + (size_t)i * 2048);
    short8 vl1 = ld8(vbase + (size_t)i * 2048 + 1024);
    short8 vh0 = ld8(vbase + (size_t)i * 2048 + 256);
    short8 vh1 = ld8(vbase + (size_t)i * 2048 + 1280);
    // weight-state transition BEFORE this tile's QK (lw enters at C-init)
    if (i == hq){
      #pragma unroll
      for (int r = 0; r < 16; r++)
        lw[r] = __builtin_amdgcn_logf(__builtin_amdgcn_exp2f(lw[r]) + wbt[r]);
    } else if (i == hq + 1){
      #pragma unroll
      for (int r = 0; r < 16; r++) lw[r] = __builtin_amdgcn_logf(wbt[r]);
    }
    f32x16 s = mfma32(kf[0], qf[0], lw);
    s = mfma32(kf[1], qf[1], s);
    s = mfma32(kf[2], qf[2], s);
    s = mfma32(kf[3], qf[3], s);
    float P[16];
    #pragma unroll
    for (int r = 0; r < 16; r++) P[r] = __builtin_amdgcn_exp2f(s[r]);
    // pack to bf16 pairs; lo lanes hold keys {0-3,8-11,16-19,24-27}, hi +4
    uint32 x0 = cvtpk_bf16(P[0],  P[1]);    // keys (0,1) | (4,5)
    uint32 x1 = cvtpk_bf16(P[2],  P[3]);    // keys (2,3) | (6,7)
    uint32 y0 = cvtpk_bf16(P[4],  P[5]);    // keys (8,9) | (12,13)
    uint32 y1 = cvtpk_bf16(P[6],  P[7]);
    uint32 x2 = cvtpk_bf16(P[8],  P[9]);    // keys (16,17) | (20,21)
    uint32 x3 = cvtpk_bf16(P[10], P[11]);
    uint32 y2 = cvtpk_bf16(P[12], P[13]);   // keys (24,25) | (28,29)
    uint32 y3 = cvtpk_bf16(P[14], P[15]);
    // swap(x,y): x -> frag word0 (keys +0,1 | +8,9), y -> word2 (keys +4,5 | +12,13)
    permswap32(x0, y0);
    permswap32(x1, y1);
    permswap32(x2, y2);
    permswap32(x3, y3);
    short8 fa0 = mk8(x0, x1, y0, y1);       // A-frag, keys i*32 + 0..15
    short8 fa1 = mk8(x2, x3, y2, y3);       // A-frag, keys i*32 + 16..31
    accLo = mfma32(fa0, vl0, accLo);
    accLo = mfma32(fa1, vl1, accLo);
    accHi = mfma32(fa0, vh0, accHi);
    accHi = mfma32(fa1, vh1, accHi);
  };
  {
    short8 kA[4], kB[4];
    #pragma unroll
    for (int f = 0; f < 4; f++) kA[f] = ld8(kp + f * 512);
    for (int i = 0; i < 32; i += 2){
      #pragma unroll
      for (int f = 0; f < 4; f++) kB[f] = ld8(kp + (size_t)(i + 1) * 2048 + f * 512);
      p2(kA, i);
      int nx = (i + 2) & 31;
      #pragma unroll
      for (int f = 0; f < 4; f++) kA[f] = ld8(kp + (size_t)nx * 2048 + f * 512);
      p2(kB, i + 1);
    }
  }

  // O C-layout: col = lane&31 = d, row = (r&3)+8*(r>>2)+4*hi = query row in tile
  int bidx = bh >> 3, h = bh & 7;
  size_t obase = ((size_t)(bidx * SEQ + qt * 32)) * DIM + h * DH + w;
  #pragma unroll
  for (int r = 0; r < 16; r++){
    int qrow = (r & 3) + 8 * (r >> 2) + 4 * hi;
    ctx[obase + (size_t)qrow * DIM]      = f2bf(accLo[r]);
    ctx[obase + (size_t)qrow * DIM + 32] = f2bf(accHi[r]);
  }
}

extern "C" void kernel_launch(void* const* d_in, const int* in_sizes, int n_in,
                              void* d_out, int out_size, void* d_ws, size_t ws_size,
                              hipStream_t stream){
  (void)in_sizes; (void)n_in; (void)out_size; (void)ws_size;
  const float* x    = (const float*)d_in[0];
  const float* ln_g = (const float*)d_in[1];
  const float* ln_b = (const float*)d_in[2];
  const float* wqkv = (const float*)d_in[3];
  const float* bqkv = (const float*)d_in[4];
  const float* wout = (const float*)d_in[5];
  const float* bout = (const float*)d_in[6];
  float* out = (float*)d_out;

  char* ws = (char*)d_ws;
  ushort_t* xn    = (ushort_t*)(ws);
  ushort_t* ctx   = (ushort_t*)(ws);              // reuse: xn dead after QKV GEMM
  ushort_t* wqkvT = (ushort_t*)(ws + 8388608);
  ushort_t* woutT = (ushort_t*)(ws + 9961472);
  ushort_t* Qb    = (ushort_t*)(ws + 10485760);
  ushort_t* Kb    = (ushort_t*)(ws + 18874368);
  ushort_t* Vtb   = (ushort_t*)(ws + 27262976);

  hipLaunchKernelGGL(prep_kernel,     dim3(3072),    dim3(256), 0, stream,
                     x, ln_g, ln_b, xn, wqkv, wqkvT, wout, woutT);
  hipLaunchKernelGGL(qkv_gemm_kernel, dim3(128, 12), dim3(256), 0, stream, xn, wqkvT, bqkv, Qb, Kb, Vtb);
  hipLaunchKernelGGL(attn_kernel,     dim3(64, 8),   dim3(256), 0, stream, Qb, Kb, Vtb, ctx);
  hipLaunchKernelGGL(out_gemm_kernel, dim3(256, 4),  dim3(256), 0, stream, ctx, woutT, bout, out);
}

// Round 18
// 142.954 us; speedup vs baseline: 1.0089x; 1.0089x over previous
//
#include <hip/hip_runtime.h>
#include <hip/hip_bf16.h>

typedef unsigned short ushort_t;
typedef unsigned int uint32;
typedef __attribute__((ext_vector_type(8))) short short8;
typedef __attribute__((ext_vector_type(4))) float f32x4;
typedef __attribute__((ext_vector_type(16))) float f32x16;

#define BATCH 8
#define SEQ 1024
#define DIM 512
#define NHEADS 8
#define DH 64
#define NQKV 1536

__device__ __forceinline__ float bf2f(ushort_t u){ return __uint_as_float(((uint32)u) << 16); }
__device__ __forceinline__ ushort_t f2bf(float f){
  uint32 u = __float_as_uint(f);
  return (ushort_t)((u + 0x7fffu + ((u >> 16) & 1u)) >> 16);
}
__device__ __forceinline__ short8 ld8(const ushort_t* p){ return *reinterpret_cast<const short8*>(p); }
__device__ __forceinline__ f32x4 mfma16(short8 a, short8 b, f32x4 c){
  return __builtin_amdgcn_mfma_f32_16x16x32_bf16(a, b, c, 0, 0, 0);
}
__device__ __forceinline__ f32x16 mfma32(short8 a, short8 b, f32x16 c){
  return __builtin_amdgcn_mfma_f32_32x32x16_bf16(a, b, c, 0, 0, 0);
}
// async global->LDS, 16 B per lane; LDS dst is wave-uniform base + lane*16.
__device__ __forceinline__ void async16(const ushort_t* g, ushort_t* l){
  __builtin_amdgcn_global_load_lds((const __attribute__((address_space(1))) void*)g,
                                   (__attribute__((address_space(3))) void*)l, 16, 0, 0);
}
__device__ __forceinline__ uint32 cvtpk_bf16(float lo, float hi){
  uint32 d;
  asm("v_cvt_pk_bf16_f32 %0, %1, %2" : "=v"(d) : "v"(lo), "v"(hi));
  return d;
}
// v_permlane32_swap_b32: a[hi lanes] <-> b[lo lanes]
__device__ __forceinline__ void permswap32(uint32& a, uint32& b){
  asm volatile("v_permlane32_swap_b32 %0, %1" : "+v"(a), "+v"(b));
}
__device__ __forceinline__ short8 mk8(uint32 a, uint32 b, uint32 c, uint32 d){
  union { uint32 u[4]; short8 v; } t;
  t.u[0] = a; t.u[1] = b; t.u[2] = c; t.u[3] = d; return t.v;
}

// ---------------- prep: LN (blocks 0..2047) + wqkv transpose (2048..2815) + wout transpose ----------------
__global__ __launch_bounds__(256) void prep_kernel(const float* __restrict__ x,
                                                   const float* __restrict__ g,
                                                   const float* __restrict__ bt,
                                                   ushort_t* __restrict__ xn,
                                                   const float* __restrict__ wqkv,
                                                   ushort_t* __restrict__ wqkvT,
                                                   const float* __restrict__ wout,
                                                   ushort_t* __restrict__ woutT){
  __shared__ float t[32][33];
  int bid = blockIdx.x;
  if (bid < 2048){
    int row  = bid * 4 + (threadIdx.x >> 6);
    int lane = threadIdx.x & 63;
    const float* xr = x + (size_t)row * DIM + lane * 8;
    float4 d0 = *reinterpret_cast<const float4*>(xr);
    float4 d1 = *reinterpret_cast<const float4*>(xr + 4);
    float v[8] = {d0.x, d0.y, d0.z, d0.w, d1.x, d1.y, d1.z, d1.w};
    float s = 0.f, ss = 0.f;
    #pragma unroll
    for (int i = 0; i < 8; i++){ s += v[i]; ss += v[i] * v[i]; }
    #pragma unroll
    for (int off = 1; off < 64; off <<= 1){ s += __shfl_xor(s, off); ss += __shfl_xor(ss, off); }
    float mean = s * (1.0f / DIM);
    float var  = ss * (1.0f / DIM) - mean * mean;
    float rstd = rsqrtf(fmaxf(var, 0.f) + 1e-5f);
    float4 g0 = *reinterpret_cast<const float4*>(g  + lane * 8);
    float4 g1 = *reinterpret_cast<const float4*>(g  + lane * 8 + 4);
    float4 b0 = *reinterpret_cast<const float4*>(bt + lane * 8);
    float4 b1 = *reinterpret_cast<const float4*>(bt + lane * 8 + 4);
    float gv[8] = {g0.x, g0.y, g0.z, g0.w, g1.x, g1.y, g1.z, g1.w};
    float bv[8] = {b0.x, b0.y, b0.z, b0.w, b1.x, b1.y, b1.z, b1.w};
    ushort_t o[8];
    #pragma unroll
    for (int i = 0; i < 8; i++) o[i] = f2bf((v[i] - mean) * rstd * gv[i] + bv[i]);
    uint4 od;
    od.x = o[0] | ((uint32)o[1] << 16); od.y = o[2] | ((uint32)o[3] << 16);
    od.z = o[4] | ((uint32)o[5] << 16); od.w = o[6] | ((uint32)o[7] << 16);
    *reinterpret_cast<uint4*>(xn + (size_t)row * DIM + lane * 8) = od;
  } else {
    const float* in; ushort_t* out; int R, C, bx, by;
    if (bid < 2816){ int b = bid - 2048; in = wqkv; out = wqkvT; R = 512; C = 1536; bx = b % 48; by = b / 48; }
    else           { int b = bid - 2816; in = wout; out = woutT; R = 512; C = 512;  bx = b % 16; by = b / 16; }
    int tx = threadIdx.x & 31, ty = threadIdx.x >> 5;
    int r0 = by * 32, c0 = bx * 32;
    #pragma unroll
    for (int i = 0; i < 4; i++) t[ty + 8*i][tx] = in[(size_t)(r0 + ty + 8*i) * C + c0 + tx];
    __syncthreads();
    #pragma unroll
    for (int i = 0; i < 4; i++) out[(size_t)(c0 + ty + 8*i) * R + r0 + tx] = f2bf(t[tx][ty + 8*i]);
  }
}

// ======================================================================
// Tiled GEMM core (m97 structure): C = A[M,512] @ Bt[N,512]^T.
// ======================================================================
template<int MT>
__device__ __forceinline__ void gemm_core_t(const ushort_t* __restrict__ A,
                                            const ushort_t* __restrict__ Bt,
                                            int m0, int n0,
                                            ushort_t* ldsA, ushort_t* ldsB,
                                            f32x4 acc[MT][4]){
  int tid = threadIdx.x, w = tid >> 6, lane = tid & 63;
  int c16 = lane & 15, quad = lane >> 4;
  int r8 = lane >> 3, p8 = lane & 7;
  int srcChunk = p8 ^ r8;                 // LDS[row][p] = G[row][p ^ (row&7)]
  int w_row = w >> 1, w_col = w & 1;

  const ushort_t* ga[MT]; const ushort_t* gb[4];
  #pragma unroll
  for (int c = 0; c < MT; c++)
    ga[c] = A  + (size_t)(m0 + c * 32 + w * 8 + r8) * DIM + srcChunk * 8;
  #pragma unroll
  for (int c = 0; c < 4; c++)
    gb[c] = Bt + (size_t)(n0 + c * 32 + w * 8 + r8) * DIM + srcChunk * 8;
  #pragma unroll
  for (int mt = 0; mt < MT; mt++)
    #pragma unroll
    for (int nt = 0; nt < 4; nt++) acc[mt][nt] = (f32x4){0.f, 0.f, 0.f, 0.f};

  for (int it = 0; it < 8; it++){         // K = 8 * 64
    #pragma unroll
    for (int c = 0; c < MT; c++){ async16(ga[c], &ldsA[(c * 32 + w * 8) * 64]); ga[c] += 64; }
    #pragma unroll
    for (int c = 0; c < 4;  c++){ async16(gb[c], &ldsB[(c * 32 + w * 8) * 64]); gb[c] += 64; }
    __syncthreads();
    #pragma unroll
    for (int kk = 0; kk < 2; kk++){
      short8 af[MT], bfr[4];
      int phys = ((kk * 4 + quad) ^ (c16 & 7)) * 8;
      #pragma unroll
      for (int mt = 0; mt < MT; mt++)
        af[mt] = ld8(&ldsA[(w_row * (MT * 16) + mt * 16 + c16) * 64 + phys]);
      #pragma unroll
      for (int nt = 0; nt < 4; nt++)
        bfr[nt] = ld8(&ldsB[(w_col * 64 + nt * 16 + c16) * 64 + phys]);
      #pragma unroll
      for (int mt = 0; mt < MT; mt++)
        #pragma unroll
        for (int nt = 0; nt < 4; nt++)
          acc[mt][nt] = mfma16(af[mt], bfr[nt], acc[mt][nt]);
    }
    __syncthreads();
  }
}

// ---------------- QKV GEMM: xn[8192,512] @ w[512,1536] + b, scatter to Q,Kb,Vt ----------------
// MT=2 (64x128 tiles, grid (128,12)): best measured (round-9 A/B). Round-17
// XCD swizzle was null (L3 absorbs A re-reads) -- plain indexing restored.
// Q pre-scaled by 0.125*log2(e). K stored FRAGMENT-BLOCKED: elem K[n][dd] at
// (n>>5)*2048 + (dd>>4)*512 + ((dd>>3)&1)*256 + (n&31)*8 + (dd&7).
__global__ __launch_bounds__(256) void qkv_gemm_kernel(const ushort_t* __restrict__ xn,
                                                       const ushort_t* __restrict__ wT,
                                                       const float* __restrict__ bias,
                                                       ushort_t* __restrict__ Qo,
                                                       ushort_t* __restrict__ Ko,
                                                       ushort_t* __restrict__ Vt){
  __shared__ __align__(16) ushort_t ldsA[64 * 64];
  __shared__ __align__(16) ushort_t ldsB[128 * 64];
  int m0 = blockIdx.x * 64, n0 = blockIdx.y * 128;
  f32x4 acc[2][4];
  gemm_core_t<2>(xn, wT, m0, n0, ldsA, ldsB, acc);

  int lane = threadIdx.x & 63, w = threadIdx.x >> 6;
  int c16 = lane & 15, quad = lane >> 4;
  int w_row = w >> 1, w_col = w & 1;
  int region = n0 >> 9;                   // 0=Q 1=K 2=V (BN=128 divides 512)

  if (region < 2){
    float sc = (region == 0) ? 0.18033688011112042f : 1.0f;   // 0.125*log2(e) folded into Q
    #pragma unroll
    for (int nt = 0; nt < 4; nt++){
      int col = n0 + w_col * 64 + nt * 16 + c16;
      float bv = bias[col];
      int cr = col & 511, h = cr >> 6, dd = cr & 63;
      #pragma unroll
      for (int mt = 0; mt < 2; mt++){
        #pragma unroll
        for (int r = 0; r < 4; r++){
          int row = m0 + w_row * 32 + mt * 16 + quad * 4 + r;
          int b = row >> 10, n = row & 1023;
          ushort_t o = f2bf((acc[mt][nt][r] + bv) * sc);
          if (region == 0){
            Qo[(((size_t)(b * NHEADS + h)) * SEQ + n) * DH + dd] = o;
          } else {
            Ko[((size_t)(b * NHEADS + h)) * SEQ * DH
               + (n >> 5) * 2048 + (dd >> 4) * 512 + ((dd >> 3) & 1) * 256
               + (n & 31) * 8 + (dd & 7)] = o;
          }
        }
      }
    }
  } else {
    #pragma unroll
    for (int nt = 0; nt < 4; nt++){
      int col = n0 + w_col * 64 + nt * 16 + c16;
      float bv = bias[col];
      int c2 = col - 1024; int h = c2 >> 6, dd = c2 & 63;
      #pragma unroll
      for (int mt = 0; mt < 2; mt++){
        int row0 = m0 + w_row * 32 + mt * 16 + quad * 4;
        int b = row0 >> 10, n = row0 & 1023;
        ushort_t o[4];
        #pragma unroll
        for (int r = 0; r < 4; r++) o[r] = f2bf(acc[mt][nt][r] + bv);
        uint2 val;
        val.x = o[0] | ((uint32)o[1] << 16);
        val.y = o[2] | ((uint32)o[3] << 16);
        *reinterpret_cast<uint2*>(Vt + (((size_t)(b * NHEADS + h)) * 128 + (n >> 3)) * 512
                                  + dd * 8 + (n & 7)) = val;
      }
    }
  }
}

// ---------------- out projection: ctx[8192,512] @ w_out[512,512] + b -> fp32 out ----------------
// MT=1 (32x128 tiles, grid (256,4)): round-4/7 config, best measured.
__global__ __launch_bounds__(256) void out_gemm_kernel(const ushort_t* __restrict__ ctx,
                                                       const ushort_t* __restrict__ wT,
                                                       const float* __restrict__ bias,
                                                       float* __restrict__ out){
  __shared__ __align__(16) ushort_t ldsA[32 * 64];
  __shared__ __align__(16) ushort_t ldsB[128 * 64];
  int m0 = blockIdx.x * 32, n0 = blockIdx.y * 128;
  f32x4 acc[1][4];
  gemm_core_t<1>(ctx, wT, m0, n0, ldsA, ldsB, acc);

  int lane = threadIdx.x & 63, w = threadIdx.x >> 6;
  int c16 = lane & 15, quad = lane >> 4;
  int w_row = w >> 1, w_col = w & 1;
  #pragma unroll
  for (int nt = 0; nt < 4; nt++){
    int col = n0 + w_col * 64 + nt * 16 + c16;
    float bv = bias[col];
    #pragma unroll
    for (int r = 0; r < 4; r++){
      int row = m0 + w_row * 16 + quad * 4 + r;
      out[(size_t)row * DIM + col] = acc[0][nt][r] + bv;
    }
  }
}

// ======================================================================
// v35 attn: SINGLE-PASS with 4 region accumulators x 2 d-halves.
// Key algebra: O = i1*S[i<=h,le] + i2*S[i<=h,ge] + i3*S[i>=h,le] +
// i4*S[i>=h,ge] where S = Sum e*mask*V is denominator-INDEPENDENT.
// Accumulate the 4 unweighted region PV sums in ONE pass (8 f32x16 accs),
// scale by i1..i4 at the end. vs v28: K bytes 256->128 KB/wave (-50%),
// exp2 1024->512 (-50%), MFMA 384->392 (QK halves, PV doubles), VALU +20%.
// Round-10 evidence says runtime ~ bytes => expect ~30-35us.
// Denominator redistribution (PV output lane = d, denom lane = query):
// 2 KB per-wave LDS table + 1 barrier (the 64KB-LDS spill trigger is 32x
// larger; GEMMs run 24KB LDS at 88 VGPR fine). Plain (256,2) -- the only
// policy that never squeezed. Grid-limited 2 waves/SIMD either way, so a
// ~240-reg allocation costs no occupancy.
// Decisive spill check: VGPR 256 + WRITE >> 8MB => falsified, revert to
// round-16 (143.0us) next round.
// ======================================================================
__global__ __launch_bounds__(256, 2) void attn_kernel(const ushort_t* __restrict__ Qg,
                                                      const ushort_t* __restrict__ Kg,
                                                      const ushort_t* __restrict__ Vtg,
                                                      ushort_t* __restrict__ ctx){
  __shared__ float sdn[4][32][4];      // per-wave query denominators (2 KB)

  int bh = blockIdx.x;                 // inner => stable XCD = bh & 7 (2MB K+V per XCD L2)
  int wv = threadIdx.x >> 6, lane = threadIdx.x & 63;
  int qt = blockIdx.y * 4 + wv;        // query image row == hq, 0..31
  int w  = lane & 31;                  // query col
  int hi = lane >> 5;
  int hq = qt;

  const ushort_t* Qh = Qg  + (size_t)bh * SEQ * DH;
  const ushort_t* Kh = Kg  + (size_t)bh * SEQ * DH;  // fragment-blocked (see qkv)
  const ushort_t* Vh = Vtg + (size_t)bh * SEQ * DH;  // blocked [n/8][dd][8]

  // Q as B-operand: B[k][j]: j=lane&31=query, k=hi*8+jj, frag f = dims f*16..f*16+15
  short8 qf[4];
  {
    const ushort_t* qp = Qh + (size_t)(qt * 32 + w) * DH + hi * 8;
    #pragma unroll
    for (int f = 0; f < 4; f++) qf[f] = ld8(qp + f * 16);
  }
  const ushort_t* kp = Kh + (size_t)lane * 8;   // + tile*2048 + f*512 (coalesced)

  // per-lane j (key col) masks: this lane's 16 S^T rows are jr = (r&3)+8*(r>>2)+4*hi
  float mle[16], mge[16];
  #pragma unroll
  for (int r = 0; r < 16; r++){
    int jr = (r & 3) + 8 * (r >> 2) + 4 * hi;
    mle[r] = (jr <= w) ? 1.f : 0.f;
    mge[r] = (jr >= w) ? 1.f : 0.f;
  }

  // 8 region accumulators: {Top,Bot} x {le,ge} x {d-lo,d-hi}
  f32x16 aTleL, aTgeL, aBleL, aBgeL, aTleH, aTgeH, aBleH, aBgeH;
  #pragma unroll
  for (int r = 0; r < 16; r++){
    aTleL[r] = 0.f; aTgeL[r] = 0.f; aBleL[r] = 0.f; aBgeL[r] = 0.f;
    aTleH[r] = 0.f; aTgeH[r] = 0.f; aBleH[r] = 0.f; aBgeH[r] = 0.f;
  }
  float tle = 0.f, tge = 0.f, ble = 0.f, bge = 0.f;
  const ushort_t* vbase = Vh + (size_t)hi * 512 + (size_t)w * 8;

  for (int i = 0; i < 32; i++){
    short8 k0 = ld8(kp + (size_t)i * 2048);
    short8 k1 = ld8(kp + (size_t)i * 2048 + 512);
    short8 k2 = ld8(kp + (size_t)i * 2048 + 1024);
    short8 k3 = ld8(kp + (size_t)i * 2048 + 1536);
    short8 vl0 = ld8(vbase + (size_t)i * 2048);
    short8 vl1 = ld8(vbase + (size_t)i * 2048 + 1024);
    short8 vh0 = ld8(vbase + (size_t)i * 2048 + 256);
    short8 vh1 = ld8(vbase + (size_t)i * 2048 + 1280);
    f32x16 s;
    #pragma unroll
    for (int r = 0; r < 16; r++) s[r] = 0.f;
    s = mfma32(k0, qf[0], s);
    s = mfma32(k1, qf[1], s);
    s = mfma32(k2, qf[2], s);
    s = mfma32(k3, qf[3], s);
    float e[16];
    float a0 = 0.f, a1 = 0.f, g0 = 0.f, g1 = 0.f;
    #pragma unroll
    for (int r = 0; r < 16; r++){
      e[r] = __builtin_amdgcn_exp2f(s[r]);
      if (r & 1){ a1 = fmaf(mle[r], e[r], a1); g1 = fmaf(mge[r], e[r], g1); }
      else      { a0 = fmaf(mle[r], e[r], a0); g0 = fmaf(mge[r], e[r], g0); }
    }
    float sle = a0 + a1, sge = g0 + g1;
    // pack P_le = e*mle and P_ge = e*mge into A-frags (v28 pack pattern)
    uint32 lx0 = cvtpk_bf16(e[0]*mle[0],   e[1]*mle[1]);
    uint32 lx1 = cvtpk_bf16(e[2]*mle[2],   e[3]*mle[3]);
    uint32 ly0 = cvtpk_bf16(e[4]*mle[4],   e[5]*mle[5]);
    uint32 ly1 = cvtpk_bf16(e[6]*mle[6],   e[7]*mle[7]);
    uint32 lx2 = cvtpk_bf16(e[8]*mle[8],   e[9]*mle[9]);
    uint32 lx3 = cvtpk_bf16(e[10]*mle[10], e[11]*mle[11]);
    uint32 ly2 = cvtpk_bf16(e[12]*mle[12], e[13]*mle[13]);
    uint32 ly3 = cvtpk_bf16(e[14]*mle[14], e[15]*mle[15]);
    permswap32(lx0, ly0); permswap32(lx1, ly1);
    permswap32(lx2, ly2); permswap32(lx3, ly3);
    short8 fle0 = mk8(lx0, lx1, ly0, ly1);
    short8 fle1 = mk8(lx2, lx3, ly2, ly3);
    uint32 gx0 = cvtpk_bf16(e[0]*mge[0],   e[1]*mge[1]);
    uint32 gx1 = cvtpk_bf16(e[2]*mge[2],   e[3]*mge[3]);
    uint32 gy0 = cvtpk_bf16(e[4]*mge[4],   e[5]*mge[5]);
    uint32 gy1 = cvtpk_bf16(e[6]*mge[6],   e[7]*mge[7]);
    uint32 gx2 = cvtpk_bf16(e[8]*mge[8],   e[9]*mge[9]);
    uint32 gx3 = cvtpk_bf16(e[10]*mge[10], e[11]*mge[11]);
    uint32 gy2 = cvtpk_bf16(e[12]*mge[12], e[13]*mge[13]);
    uint32 gy3 = cvtpk_bf16(e[14]*mge[14], e[15]*mge[15]);
    permswap32(gx0, gy0); permswap32(gx1, gy1);
    permswap32(gx2, gy2); permswap32(gx3, gy3);
    short8 fge0 = mk8(gx0, gx1, gy0, gy1);
    short8 fge1 = mk8(gx2, gx3, gy2, gy3);
    if (i <= hq){                       // uniform branch: top regions
      tle += sle; tge += sge;
      aTleL = mfma32(fle0, vl0, aTleL); aTleL = mfma32(fle1, vl1, aTleL);
      aTleH = mfma32(fle0, vh0, aTleH); aTleH = mfma32(fle1, vh1, aTleH);
      aTgeL = mfma32(fge0, vl0, aTgeL); aTgeL = mfma32(fge1, vl1, aTgeL);
      aTgeH = mfma32(fge0, vh0, aTgeH); aTgeH = mfma32(fge1, vh1, aTgeH);
    }
    if (i >= hq){                       // uniform branch: bottom regions (both at i==hq)
      ble += sle; bge += sge;
      aBleL = mfma32(fle0, vl0, aBleL); aBleL = mfma32(fle1, vl1, aBleL);
      aBleH = mfma32(fle0, vh0, aBleH); aBleH = mfma32(fle1, vh1, aBleH);
      aBgeL = mfma32(fge0, vl0, aBgeL); aBgeL = mfma32(fge1, vl1, aBgeL);
      aBgeH = mfma32(fge0, vh0, aBgeH); aBgeH = mfma32(fge1, vh1, aBgeH);
    }
  }

  // combine the two lane-halves (same query, complementary key rows)
  tle += __shfl_xor(tle, 32); tge += __shfl_xor(tge, 32);
  ble += __shfl_xor(ble, 32); bge += __shfl_xor(bge, 32);
  float i1 = 0.25f / fmaxf(tle, 1e-30f);   // region (i<=h, j<=w), /4 folded in
  float i2 = 0.25f / fmaxf(tge, 1e-30f);   // (i<=h, j>=w)
  float i3 = 0.25f / fmaxf(ble, 1e-30f);   // (i>=h, j<=w)
  float i4 = 0.25f / fmaxf(bge, 1e-30f);   // (i>=h, j>=w)

  // redistribute: O element rows are queries qrow(r,hi), but denominators
  // live in lane = query. Per-wave LDS table, block barrier, read back.
  if (lane < 32){
    float4 d4 = {i1, i2, i3, i4};
    *reinterpret_cast<float4*>(&sdn[wv][w][0]) = d4;
  }
  __syncthreads();

  int bidx = bh >> 3, h = bh & 7;
  size_t obase = ((size_t)(bidx * SEQ + qt * 32)) * DIM + h * DH + w;
  #pragma unroll
  for (int r = 0; r < 16; r++){
    int qrow = (r & 3) + 8 * (r >> 2) + 4 * hi;
    float4 dn = *reinterpret_cast<const float4*>(&sdn[wv][qrow][0]);
    float oL = dn.x * aTleL[r] + dn.y * aTgeL[r] + dn.z * aBleL[r] + dn.w * aBgeL[r];
    float oH = dn.x * aTleH[r] + dn.y * aTgeH[r] + dn.z * aBleH[r] + dn.w * aBgeH[r];
    ctx[obase + (size_t)qrow * DIM]      = f2bf(oL);
    ctx[obase + (size_t)qrow * DIM + 32] = f2bf(oH);
  }
}

extern "C" void kernel_launch(void* const* d_in, const int* in_sizes, int n_in,
                              void* d_out, int out_size, void* d_ws, size_t ws_size,
                              hipStream_t stream){
  (void)in_sizes; (void)n_in; (void)out_size; (void)ws_size;
  const float* x    = (const float*)d_in[0];
  const float* ln_g = (const float*)d_in[1];
  const float* ln_b = (const float*)d_in[2];
  const float* wqkv = (const float*)d_in[3];
  const float* bqkv = (const float*)d_in[4];
  const float* wout = (const float*)d_in[5];
  const float* bout = (const float*)d_in[6];
  float* out = (float*)d_out;

  char* ws = (char*)d_ws;
  ushort_t* xn    = (ushort_t*)(ws);
  ushort_t* ctx   = (ushort_t*)(ws);              // reuse: xn dead after QKV GEMM
  ushort_t* wqkvT = (ushort_t*)(ws + 8388608);
  ushort_t* woutT = (ushort_t*)(ws + 9961472);
  ushort_t* Qb    = (ushort_t*)(ws + 10485760);
  ushort_t* Kb    = (ushort_t*)(ws + 18874368);
  ushort_t* Vtb   = (ushort_t*)(ws + 27262976);

  hipLaunchKernelGGL(prep_kernel,     dim3(3072),    dim3(256), 0, stream,
                     x, ln_g, ln_b, xn, wqkv, wqkvT, wout, woutT);
  hipLaunchKernelGGL(qkv_gemm_kernel, dim3(128, 12), dim3(256), 0, stream, xn, wqkvT, bqkv, Qb, Kb, Vtb);
  hipLaunchKernelGGL(attn_kernel,     dim3(64, 8),   dim3(256), 0, stream, Qb, Kb, Vtb, ctx);
  hipLaunchKernelGGL(out_gemm_kernel, dim3(256, 4),  dim3(256), 0, stream, ctx, woutT, bout, out);
}

// Round 19
// 142.500 us; speedup vs baseline: 1.0121x; 1.0032x over previous
//
#include <hip/hip_runtime.h>
#include <hip/hip_bf16.h>

typedef unsigned short ushort_t;
typedef unsigned int uint32;
typedef __attribute__((ext_vector_type(8))) short short8;
typedef __attribute__((ext_vector_type(4))) float f32x4;
typedef __attribute__((ext_vector_type(16))) float f32x16;

#define BATCH 8
#define SEQ 1024
#define DIM 512
#define NHEADS 8
#define DH 64
#define NQKV 1536

__device__ __forceinline__ float bf2f(ushort_t u){ return __uint_as_float(((uint32)u) << 16); }
__device__ __forceinline__ ushort_t f2bf(float f){
  uint32 u = __float_as_uint(f);
  return (ushort_t)((u + 0x7fffu + ((u >> 16) & 1u)) >> 16);
}
__device__ __forceinline__ short8 ld8(const ushort_t* p){ return *reinterpret_cast<const short8*>(p); }
__device__ __forceinline__ f32x4 mfma16(short8 a, short8 b, f32x4 c){
  return __builtin_amdgcn_mfma_f32_16x16x32_bf16(a, b, c, 0, 0, 0);
}
__device__ __forceinline__ f32x16 mfma32(short8 a, short8 b, f32x16 c){
  return __builtin_amdgcn_mfma_f32_32x32x16_bf16(a, b, c, 0, 0, 0);
}
// async global->LDS, 16 B per lane; LDS dst is wave-uniform base + lane*16.
__device__ __forceinline__ void async16(const ushort_t* g, ushort_t* l){
  __builtin_amdgcn_global_load_lds((const __attribute__((address_space(1))) void*)g,
                                   (__attribute__((address_space(3))) void*)l, 16, 0, 0);
}
__device__ __forceinline__ uint32 cvtpk_bf16(float lo, float hi){
  uint32 d;
  asm("v_cvt_pk_bf16_f32 %0, %1, %2" : "=v"(d) : "v"(lo), "v"(hi));
  return d;
}
// v_permlane32_swap_b32: a[hi lanes] <-> b[lo lanes]
__device__ __forceinline__ void permswap32(uint32& a, uint32& b){
  asm volatile("v_permlane32_swap_b32 %0, %1" : "+v"(a), "+v"(b));
}
__device__ __forceinline__ short8 mk8(uint32 a, uint32 b, uint32 c, uint32 d){
  union { uint32 u[4]; short8 v; } t;
  t.u[0] = a; t.u[1] = b; t.u[2] = c; t.u[3] = d; return t.v;
}

// ---------------- prep: LN (blocks 0..2047) + wqkv transpose (2048..2815) + wout transpose ----------------
__global__ __launch_bounds__(256) void prep_kernel(const float* __restrict__ x,
                                                   const float* __restrict__ g,
                                                   const float* __restrict__ bt,
                                                   ushort_t* __restrict__ xn,
                                                   const float* __restrict__ wqkv,
                                                   ushort_t* __restrict__ wqkvT,
                                                   const float* __restrict__ wout,
                                                   ushort_t* __restrict__ woutT){
  __shared__ float t[32][33];
  int bid = blockIdx.x;
  if (bid < 2048){
    int row  = bid * 4 + (threadIdx.x >> 6);
    int lane = threadIdx.x & 63;
    const float* xr = x + (size_t)row * DIM + lane * 8;
    float4 d0 = *reinterpret_cast<const float4*>(xr);
    float4 d1 = *reinterpret_cast<const float4*>(xr + 4);
    float v[8] = {d0.x, d0.y, d0.z, d0.w, d1.x, d1.y, d1.z, d1.w};
    float s = 0.f, ss = 0.f;
    #pragma unroll
    for (int i = 0; i < 8; i++){ s += v[i]; ss += v[i] * v[i]; }
    #pragma unroll
    for (int off = 1; off < 64; off <<= 1){ s += __shfl_xor(s, off); ss += __shfl_xor(ss, off); }
    float mean = s * (1.0f / DIM);
    float var  = ss * (1.0f / DIM) - mean * mean;
    float rstd = rsqrtf(fmaxf(var, 0.f) + 1e-5f);
    float4 g0 = *reinterpret_cast<const float4*>(g  + lane * 8);
    float4 g1 = *reinterpret_cast<const float4*>(g  + lane * 8 + 4);
    float4 b0 = *reinterpret_cast<const float4*>(bt + lane * 8);
    float4 b1 = *reinterpret_cast<const float4*>(bt + lane * 8 + 4);
    float gv[8] = {g0.x, g0.y, g0.z, g0.w, g1.x, g1.y, g1.z, g1.w};
    float bv[8] = {b0.x, b0.y, b0.z, b0.w, b1.x, b1.y, b1.z, b1.w};
    ushort_t o[8];
    #pragma unroll
    for (int i = 0; i < 8; i++) o[i] = f2bf((v[i] - mean) * rstd * gv[i] + bv[i]);
    uint4 od;
    od.x = o[0] | ((uint32)o[1] << 16); od.y = o[2] | ((uint32)o[3] << 16);
    od.z = o[4] | ((uint32)o[5] << 16); od.w = o[6] | ((uint32)o[7] << 16);
    *reinterpret_cast<uint4*>(xn + (size_t)row * DIM + lane * 8) = od;
  } else {
    const float* in; ushort_t* out; int R, C, bx, by;
    if (bid < 2816){ int b = bid - 2048; in = wqkv; out = wqkvT; R = 512; C = 1536; bx = b % 48; by = b / 48; }
    else           { int b = bid - 2816; in = wout; out = woutT; R = 512; C = 512;  bx = b % 16; by = b / 16; }
    int tx = threadIdx.x & 31, ty = threadIdx.x >> 5;
    int r0 = by * 32, c0 = bx * 32;
    #pragma unroll
    for (int i = 0; i < 4; i++) t[ty + 8*i][tx] = in[(size_t)(r0 + ty + 8*i) * C + c0 + tx];
    __syncthreads();
    #pragma unroll
    for (int i = 0; i < 4; i++) out[(size_t)(c0 + ty + 8*i) * R + r0 + tx] = f2bf(t[tx][ty + 8*i]);
  }
}

// ======================================================================
// Tiled GEMM core (m97 structure): C = A[M,512] @ Bt[N,512]^T.
// ======================================================================
template<int MT>
__device__ __forceinline__ void gemm_core_t(const ushort_t* __restrict__ A,
                                            const ushort_t* __restrict__ Bt,
                                            int m0, int n0,
                                            ushort_t* ldsA, ushort_t* ldsB,
                                            f32x4 acc[MT][4]){
  int tid = threadIdx.x, w = tid >> 6, lane = tid & 63;
  int c16 = lane & 15, quad = lane >> 4;
  int r8 = lane >> 3, p8 = lane & 7;
  int srcChunk = p8 ^ r8;                 // LDS[row][p] = G[row][p ^ (row&7)]
  int w_row = w >> 1, w_col = w & 1;

  const ushort_t* ga[MT]; const ushort_t* gb[4];
  #pragma unroll
  for (int c = 0; c < MT; c++)
    ga[c] = A  + (size_t)(m0 + c * 32 + w * 8 + r8) * DIM + srcChunk * 8;
  #pragma unroll
  for (int c = 0; c < 4; c++)
    gb[c] = Bt + (size_t)(n0 + c * 32 + w * 8 + r8) * DIM + srcChunk * 8;
  #pragma unroll
  for (int mt = 0; mt < MT; mt++)
    #pragma unroll
    for (int nt = 0; nt < 4; nt++) acc[mt][nt] = (f32x4){0.f, 0.f, 0.f, 0.f};

  for (int it = 0; it < 8; it++){         // K = 8 * 64
    #pragma unroll
    for (int c = 0; c < MT; c++){ async16(ga[c], &ldsA[(c * 32 + w * 8) * 64]); ga[c] += 64; }
    #pragma unroll
    for (int c = 0; c < 4;  c++){ async16(gb[c], &ldsB[(c * 32 + w * 8) * 64]); gb[c] += 64; }
    __syncthreads();
    #pragma unroll
    for (int kk = 0; kk < 2; kk++){
      short8 af[MT], bfr[4];
      int phys = ((kk * 4 + quad) ^ (c16 & 7)) * 8;
      #pragma unroll
      for (int mt = 0; mt < MT; mt++)
        af[mt] = ld8(&ldsA[(w_row * (MT * 16) + mt * 16 + c16) * 64 + phys]);
      #pragma unroll
      for (int nt = 0; nt < 4; nt++)
        bfr[nt] = ld8(&ldsB[(w_col * 64 + nt * 16 + c16) * 64 + phys]);
      #pragma unroll
      for (int mt = 0; mt < MT; mt++)
        #pragma unroll
        for (int nt = 0; nt < 4; nt++)
          acc[mt][nt] = mfma16(af[mt], bfr[nt], acc[mt][nt]);
    }
    __syncthreads();
  }
}

// ---------------- QKV GEMM: xn[8192,512] @ w[512,1536] + b, scatter to Q,Kb,Vt ----------------
// MT=2 (64x128 tiles, grid (128,12)): best measured (round-9 A/B). Round-17
// XCD swizzle was null (L3 absorbs A re-reads) -- plain indexing restored.
// Q pre-scaled by 0.125*log2(e). K stored FRAGMENT-BLOCKED: elem K[n][dd] at
// (n>>5)*2048 + (dd>>4)*512 + ((dd>>3)&1)*256 + (n&31)*8 + (dd&7).
__global__ __launch_bounds__(256) void qkv_gemm_kernel(const ushort_t* __restrict__ xn,
                                                       const ushort_t* __restrict__ wT,
                                                       const float* __restrict__ bias,
                                                       ushort_t* __restrict__ Qo,
                                                       ushort_t* __restrict__ Ko,
                                                       ushort_t* __restrict__ Vt){
  __shared__ __align__(16) ushort_t ldsA[64 * 64];
  __shared__ __align__(16) ushort_t ldsB[128 * 64];
  int m0 = blockIdx.x * 64, n0 = blockIdx.y * 128;
  f32x4 acc[2][4];
  gemm_core_t<2>(xn, wT, m0, n0, ldsA, ldsB, acc);

  int lane = threadIdx.x & 63, w = threadIdx.x >> 6;
  int c16 = lane & 15, quad = lane >> 4;
  int w_row = w >> 1, w_col = w & 1;
  int region = n0 >> 9;                   // 0=Q 1=K 2=V (BN=128 divides 512)

  if (region < 2){
    float sc = (region == 0) ? 0.18033688011112042f : 1.0f;   // 0.125*log2(e) folded into Q
    #pragma unroll
    for (int nt = 0; nt < 4; nt++){
      int col = n0 + w_col * 64 + nt * 16 + c16;
      float bv = bias[col];
      int cr = col & 511, h = cr >> 6, dd = cr & 63;
      #pragma unroll
      for (int mt = 0; mt < 2; mt++){
        #pragma unroll
        for (int r = 0; r < 4; r++){
          int row = m0 + w_row * 32 + mt * 16 + quad * 4 + r;
          int b = row >> 10, n = row & 1023;
          ushort_t o = f2bf((acc[mt][nt][r] + bv) * sc);
          if (region == 0){
            Qo[(((size_t)(b * NHEADS + h)) * SEQ + n) * DH + dd] = o;
          } else {
            Ko[((size_t)(b * NHEADS + h)) * SEQ * DH
               + (n >> 5) * 2048 + (dd >> 4) * 512 + ((dd >> 3) & 1) * 256
               + (n & 31) * 8 + (dd & 7)] = o;
          }
        }
      }
    }
  } else {
    #pragma unroll
    for (int nt = 0; nt < 4; nt++){
      int col = n0 + w_col * 64 + nt * 16 + c16;
      float bv = bias[col];
      int c2 = col - 1024; int h = c2 >> 6, dd = c2 & 63;
      #pragma unroll
      for (int mt = 0; mt < 2; mt++){
        int row0 = m0 + w_row * 32 + mt * 16 + quad * 4;
        int b = row0 >> 10, n = row0 & 1023;
        ushort_t o[4];
        #pragma unroll
        for (int r = 0; r < 4; r++) o[r] = f2bf(acc[mt][nt][r] + bv);
        uint2 val;
        val.x = o[0] | ((uint32)o[1] << 16);
        val.y = o[2] | ((uint32)o[3] << 16);
        *reinterpret_cast<uint2*>(Vt + (((size_t)(b * NHEADS + h)) * 128 + (n >> 3)) * 512
                                  + dd * 8 + (n & 7)) = val;
      }
    }
  }
}

// ---------------- out projection: ctx[8192,512] @ w_out[512,512] + b -> fp32 out ----------------
// MT=1 (32x128 tiles, grid (256,4)): round-4/7 config, best measured.
__global__ __launch_bounds__(256) void out_gemm_kernel(const ushort_t* __restrict__ ctx,
                                                       const ushort_t* __restrict__ wT,
                                                       const float* __restrict__ bias,
                                                       float* __restrict__ out){
  __shared__ __align__(16) ushort_t ldsA[32 * 64];
  __shared__ __align__(16) ushort_t ldsB[128 * 64];
  int m0 = blockIdx.x * 32, n0 = blockIdx.y * 128;
  f32x4 acc[1][4];
  gemm_core_t<1>(ctx, wT, m0, n0, ldsA, ldsB, acc);

  int lane = threadIdx.x & 63, w = threadIdx.x >> 6;
  int c16 = lane & 15, quad = lane >> 4;
  int w_row = w >> 1, w_col = w & 1;
  #pragma unroll
  for (int nt = 0; nt < 4; nt++){
    int col = n0 + w_col * 64 + nt * 16 + c16;
    float bv = bias[col];
    #pragma unroll
    for (int r = 0; r < 4; r++){
      int row = m0 + w_row * 16 + quad * 4 + r;
      out[(size_t)row * DIM + col] = acc[0][nt][r] + bv;
    }
  }
}

// ======================================================================
// FINAL attn == v35 (confirmation of best measured total, 142.95us):
// SINGLE-PASS with 4 region accumulators x 2 d-halves.
// O = i1*S[Top,le] + i2*S[Top,ge] + i3*S[Bot,le] + i4*S[Bot,ge], where
// each S = Sum e*mask*V is denominator-independent -- accumulate all 4
// unweighted, scale exactly in f32 at the end. 1 barrier, 2 KB LDS.
// Ablation matrix closed: bytes -50% (this) null, occupancy x2 (v25)
// null, exp2 -50% (this) null, MFMA ~constant across all -- the kernel
// is issue-balanced (~70% combined VALU+MFMA) at the structural minimum
// instruction count for this decomposition. K-LDS staging is compiler-
// blocked (VGPR/LDS coupling, 4 attempts); splits and MT=4 refuted.
// Session: 188.4 -> ~143us (-24%).
// ======================================================================
__global__ __launch_bounds__(256, 2) void attn_kernel(const ushort_t* __restrict__ Qg,
                                                      const ushort_t* __restrict__ Kg,
                                                      const ushort_t* __restrict__ Vtg,
                                                      ushort_t* __restrict__ ctx){
  __shared__ float sdn[4][32][4];      // per-wave query denominators (2 KB)

  int bh = blockIdx.x;                 // inner => stable XCD = bh & 7 (2MB K+V per XCD L2)
  int wv = threadIdx.x >> 6, lane = threadIdx.x & 63;
  int qt = blockIdx.y * 4 + wv;        // query image row == hq, 0..31
  int w  = lane & 31;                  // query col
  int hi = lane >> 5;
  int hq = qt;

  const ushort_t* Qh = Qg  + (size_t)bh * SEQ * DH;
  const ushort_t* Kh = Kg  + (size_t)bh * SEQ * DH;  // fragment-blocked (see qkv)
  const ushort_t* Vh = Vtg + (size_t)bh * SEQ * DH;  // blocked [n/8][dd][8]

  // Q as B-operand: B[k][j]: j=lane&31=query, k=hi*8+jj, frag f = dims f*16..f*16+15
  short8 qf[4];
  {
    const ushort_t* qp = Qh + (size_t)(qt * 32 + w) * DH + hi * 8;
    #pragma unroll
    for (int f = 0; f < 4; f++) qf[f] = ld8(qp + f * 16);
  }
  const ushort_t* kp = Kh + (size_t)lane * 8;   // + tile*2048 + f*512 (coalesced)

  // per-lane j (key col) masks: this lane's 16 S^T rows are jr = (r&3)+8*(r>>2)+4*hi
  float mle[16], mge[16];
  #pragma unroll
  for (int r = 0; r < 16; r++){
    int jr = (r & 3) + 8 * (r >> 2) + 4 * hi;
    mle[r] = (jr <= w) ? 1.f : 0.f;
    mge[r] = (jr >= w) ? 1.f : 0.f;
  }

  // 8 region accumulators: {Top,Bot} x {le,ge} x {d-lo,d-hi}
  f32x16 aTleL, aTgeL, aBleL, aBgeL, aTleH, aTgeH, aBleH, aBgeH;
  #pragma unroll
  for (int r = 0; r < 16; r++){
    aTleL[r] = 0.f; aTgeL[r] = 0.f; aBleL[r] = 0.f; aBgeL[r] = 0.f;
    aTleH[r] = 0.f; aTgeH[r] = 0.f; aBleH[r] = 0.f; aBgeH[r] = 0.f;
  }
  float tle = 0.f, tge = 0.f, ble = 0.f, bge = 0.f;
  const ushort_t* vbase = Vh + (size_t)hi * 512 + (size_t)w * 8;

  for (int i = 0; i < 32; i++){
    short8 k0 = ld8(kp + (size_t)i * 2048);
    short8 k1 = ld8(kp + (size_t)i * 2048 + 512);
    short8 k2 = ld8(kp + (size_t)i * 2048 + 1024);
    short8 k3 = ld8(kp + (size_t)i * 2048 + 1536);
    short8 vl0 = ld8(vbase + (size_t)i * 2048);
    short8 vl1 = ld8(vbase + (size_t)i * 2048 + 1024);
    short8 vh0 = ld8(vbase + (size_t)i * 2048 + 256);
    short8 vh1 = ld8(vbase + (size_t)i * 2048 + 1280);
    f32x16 s;
    #pragma unroll
    for (int r = 0; r < 16; r++) s[r] = 0.f;
    s = mfma32(k0, qf[0], s);
    s = mfma32(k1, qf[1], s);
    s = mfma32(k2, qf[2], s);
    s = mfma32(k3, qf[3], s);
    float e[16];
    float a0 = 0.f, a1 = 0.f, g0 = 0.f, g1 = 0.f;
    #pragma unroll
    for (int r = 0; r < 16; r++){
      e[r] = __builtin_amdgcn_exp2f(s[r]);
      if (r & 1){ a1 = fmaf(mle[r], e[r], a1); g1 = fmaf(mge[r], e[r], g1); }
      else      { a0 = fmaf(mle[r], e[r], a0); g0 = fmaf(mge[r], e[r], g0); }
    }
    float sle = a0 + a1, sge = g0 + g1;
    // pack P_le = e*mle and P_ge = e*mge into A-frags (v28 pack pattern)
    uint32 lx0 = cvtpk_bf16(e[0]*mle[0],   e[1]*mle[1]);
    uint32 lx1 = cvtpk_bf16(e[2]*mle[2],   e[3]*mle[3]);
    uint32 ly0 = cvtpk_bf16(e[4]*mle[4],   e[5]*mle[5]);
    uint32 ly1 = cvtpk_bf16(e[6]*mle[6],   e[7]*mle[7]);
    uint32 lx2 = cvtpk_bf16(e[8]*mle[8],   e[9]*mle[9]);
    uint32 lx3 = cvtpk_bf16(e[10]*mle[10], e[11]*mle[11]);
    uint32 ly2 = cvtpk_bf16(e[12]*mle[12], e[13]*mle[13]);
    uint32 ly3 = cvtpk_bf16(e[14]*mle[14], e[15]*mle[15]);
    permswap32(lx0, ly0); permswap32(lx1, ly1);
    permswap32(lx2, ly2); permswap32(lx3, ly3);
    short8 fle0 = mk8(lx0, lx1, ly0, ly1);
    short8 fle1 = mk8(lx2, lx3, ly2, ly3);
    uint32 gx0 = cvtpk_bf16(e[0]*mge[0],   e[1]*mge[1]);
    uint32 gx1 = cvtpk_bf16(e[2]*mge[2],   e[3]*mge[3]);
    uint32 gy0 = cvtpk_bf16(e[4]*mge[4],   e[5]*mge[5]);
    uint32 gy1 = cvtpk_bf16(e[6]*mge[6],   e[7]*mge[7]);
    uint32 gx2 = cvtpk_bf16(e[8]*mge[8],   e[9]*mge[9]);
    uint32 gx3 = cvtpk_bf16(e[10]*mge[10], e[11]*mge[11]);
    uint32 gy2 = cvtpk_bf16(e[12]*mge[12], e[13]*mge[13]);
    uint32 gy3 = cvtpk_bf16(e[14]*mge[14], e[15]*mge[15]);
    permswap32(gx0, gy0); permswap32(gx1, gy1);
    permswap32(gx2, gy2); permswap32(gx3, gy3);
    short8 fge0 = mk8(gx0, gx1, gy0, gy1);
    short8 fge1 = mk8(gx2, gx3, gy2, gy3);
    if (i <= hq){                       // uniform branch: top regions
      tle += sle; tge += sge;
      aTleL = mfma32(fle0, vl0, aTleL); aTleL = mfma32(fle1, vl1, aTleL);
      aTleH = mfma32(fle0, vh0, aTleH); aTleH = mfma32(fle1, vh1, aTleH);
      aTgeL = mfma32(fge0, vl0, aTgeL); aTgeL = mfma32(fge1, vl1, aTgeL);
      aTgeH = mfma32(fge0, vh0, aTgeH); aTgeH = mfma32(fge1, vh1, aTgeH);
    }
    if (i >= hq){                       // uniform branch: bottom regions (both at i==hq)
      ble += sle; bge += sge;
      aBleL = mfma32(fle0, vl0, aBleL); aBleL = mfma32(fle1, vl1, aBleL);
      aBleH = mfma32(fle0, vh0, aBleH); aBleH = mfma32(fle1, vh1, aBleH);
      aBgeL = mfma32(fge0, vl0, aBgeL); aBgeL = mfma32(fge1, vl1, aBgeL);
      aBgeH = mfma32(fge0, vh0, aBgeH); aBgeH = mfma32(fge1, vh1, aBgeH);
    }
  }

  // combine the two lane-halves (same query, complementary key rows)
  tle += __shfl_xor(tle, 32); tge += __shfl_xor(tge, 32);
  ble += __shfl_xor(ble, 32); bge += __shfl_xor(bge, 32);
  float i1 = 0.25f / fmaxf(tle, 1e-30f);   // region (i<=h, j<=w), /4 folded in
  float i2 = 0.25f / fmaxf(tge, 1e-30f);   // (i<=h, j>=w)
  float i3 = 0.25f / fmaxf(ble, 1e-30f);   // (i>=h, j<=w)
  float i4 = 0.25f / fmaxf(bge, 1e-30f);   // (i>=h, j>=w)

  // redistribute: O element rows are queries qrow(r,hi), but denominators
  // live in lane = query. Per-wave LDS table, block barrier, read back.
  if (lane < 32){
    float4 d4 = {i1, i2, i3, i4};
    *reinterpret_cast<float4*>(&sdn[wv][w][0]) = d4;
  }
  __syncthreads();

  int bidx = bh >> 3, h = bh & 7;
  size_t obase = ((size_t)(bidx * SEQ + qt * 32)) * DIM + h * DH + w;
  #pragma unroll
  for (int r = 0; r < 16; r++){
    int qrow = (r & 3) + 8 * (r >> 2) + 4 * hi;
    float4 dn = *reinterpret_cast<const float4*>(&sdn[wv][qrow][0]);
    float oL = dn.x * aTleL[r] + dn.y * aTgeL[r] + dn.z * aBleL[r] + dn.w * aBgeL[r];
    float oH = dn.x * aTleH[r] + dn.y * aTgeH[r] + dn.z * aBleH[r] + dn.w * aBgeH[r];
    ctx[obase + (size_t)qrow * DIM]      = f2bf(oL);
    ctx[obase + (size_t)qrow * DIM + 32] = f2bf(oH);
  }
}

extern "C" void kernel_launch(void* const* d_in, const int* in_sizes, int n_in,
                              void* d_out, int out_size, void* d_ws, size_t ws_size,
                              hipStream_t stream){
  (void)in_sizes; (void)n_in; (void)out_size; (void)ws_size;
  const float* x    = (const float*)d_in[0];
  const float* ln_g = (const float*)d_in[1];
  const float* ln_b = (const float*)d_in[2];
  const float* wqkv = (const float*)d_in[3];
  const float* bqkv = (const float*)d_in[4];
  const float* wout = (const float*)d_in[5];
  const float* bout = (const float*)d_in[6];
  float* out = (float*)d_out;

  char* ws = (char*)d_ws;
  ushort_t* xn    = (ushort_t*)(ws);
  ushort_t* ctx   = (ushort_t*)(ws);              // reuse: xn dead after QKV GEMM
  ushort_t* wqkvT = (ushort_t*)(ws + 8388608);
  ushort_t* woutT = (ushort_t*)(ws + 9961472);
  ushort_t* Qb    = (ushort_t*)(ws + 10485760);
  ushort_t* Kb    = (ushort_t*)(ws + 18874368);
  ushort_t* Vtb   = (ushort_t*)(ws + 27262976);

  hipLaunchKernelGGL(prep_kernel,     dim3(3072),    dim3(256), 0, stream,
                     x, ln_g, ln_b, xn, wqkv, wqkvT, wout, woutT);
  hipLaunchKernelGGL(qkv_gemm_kernel, dim3(128, 12), dim3(256), 0, stream, xn, wqkvT, bqkv, Qb, Kb, Vtb);
  hipLaunchKernelGGL(attn_kernel,     dim3(64, 8),   dim3(256), 0, stream, Qb, Kb, Vtb, ctx);
  hipLaunchKernelGGL(out_gemm_kernel, dim3(256, 4),  dim3(256), 0, stream, ctx, woutT, bout, out);
}